// Round 21
// baseline (3553.358 us; speedup 1.0000x reference)
//
#include <hip/hip_runtime.h>

#define B_ 16
#define S_ 256
#define H_ 768
#define NH_ 12
#define DH_ 64
#define L_ 12
#define FF_ 3072
#define T_ 9
#define NTOK (B_*S_)

#define AS1 __attribute__((address_space(1)))
#define AS3 __attribute__((address_space(3)))

typedef __attribute__((ext_vector_type(8))) short bfrag;
typedef __attribute__((ext_vector_type(8))) unsigned short us8;
typedef __attribute__((ext_vector_type(4))) float f4;

#define LOG2E_ 1.4426950408889634f
#define LN2_   0.6931471805599453f

__device__ inline unsigned short f2bf(float x) {
    unsigned u = __builtin_bit_cast(unsigned, x);
    return (unsigned short)((u + 0x7fffu + ((u >> 16) & 1u)) >> 16);
}
__device__ inline float bf2f(unsigned short h) {
    unsigned u = ((unsigned)h) << 16;
    return __builtin_bit_cast(float, u);
}
__device__ inline void pack8(const float* v, us8& h, us8& l) {
    #pragma unroll
    for (int j = 0; j < 8; j++) {
        unsigned short hh = f2bf(v[j]);
        h[j] = hh;
        l[j] = f2bf(v[j] - bf2f(hh));
    }
}

// ================= weight convert =================
__global__ __launch_bounds__(256) void k_conv_w(
    const float* __restrict__ Wq, const float* __restrict__ Wk,
    const float* __restrict__ Wv, const float* __restrict__ Wo,
    const float* __restrict__ Wi, const float* __restrict__ Wf,
    const float* __restrict__ bq, const float* __restrict__ bk, const float* __restrict__ bv,
    float* __restrict__ qkvbias, unsigned short* __restrict__ Wpk)
{
    int bid = blockIdx.x;
    int tid = threadIdx.x;
    if (bid == 0) {
        for (int i = tid; i < 3 * H_; i += 256)
            qkvbias[i] = (i < H_) ? bq[i] : (i < 2 * H_) ? bk[i - H_] : bv[i - 2 * H_];
    }
    const float* src; int Kd, Nd; size_t doff; int t;
    if (bid < 576)       { int m = bid / 144; src = (m == 0) ? Wq : (m == 1) ? Wk : (m == 2) ? Wv : Wo;
                           Kd = H_; Nd = H_; doff = (size_t)m * 73728; t = bid % 144; }
    else if (bid < 1152) { src = Wi; Kd = H_; Nd = FF_; doff = 294912; t = bid - 576; }
    else                 { src = Wf; Kd = FF_; Nd = H_; doff = 589824; t = bid - 1152; }
    int ntn = Nd / 64;
    int tk = t / ntn, tn = t % ntn;
    int k0 = tk * 64, n0 = tn * 64;
    __shared__ float tile[64][65];
    int r = tid >> 6, c = tid & 63;
    #pragma unroll
    for (int i = 0; i < 16; i++)
        tile[r + i * 4][c] = src[(size_t)(k0 + r + i * 4) * Nd + n0 + c];
    __syncthreads();
    #pragma unroll
    for (int e = 0; e < 2; e++) {
        int item = tid * 2 + e;
        int nl = item >> 3, kb = item & 7;
        float v8[8];
        #pragma unroll
        for (int j = 0; j < 8; j++) v8[j] = tile[kb * 8 + j][nl];
        us8 h, l; pack8(v8, h, l);
        unsigned short* p = Wpk + (doff + (size_t)(n0 + nl) * (Kd / 8) + (k0 / 8 + kb)) * 16;
        *reinterpret_cast<us8*>(p) = h;
        *reinterpret_cast<us8*>(p + 8) = l;
    }
}

// ================= embedding + LN (packed only) =================
__global__ __launch_bounds__(128) void k_embed_ln(
    const int* __restrict__ ids, const float* __restrict__ wemb,
    const float* __restrict__ pemb, const float* __restrict__ temb,
    const float* __restrict__ g, const float* __restrict__ bb,
    unsigned short* __restrict__ out_pk)
{
    int tok = blockIdx.x;
    int s = tok & (S_ - 1);
    int id = ids[tok];
    int tid = threadIdx.x;
    bool act = tid < 96;
    int idx = tid * 8;
    float v8[8];
    float sum = 0.f;
    if (act) {
        const float4* w4 = reinterpret_cast<const float4*>(wemb + (size_t)id * H_ + idx);
        const float4* p4 = reinterpret_cast<const float4*>(pemb + (size_t)s * H_ + idx);
        const float4* t4 = reinterpret_cast<const float4*>(temb + idx);
        #pragma unroll
        for (int q = 0; q < 2; q++) {
            float4 a = w4[q], b = p4[q], c = t4[q];
            v8[q*4+0] = a.x + b.x + c.x; v8[q*4+1] = a.y + b.y + c.y;
            v8[q*4+2] = a.z + b.z + c.z; v8[q*4+3] = a.w + b.w + c.w;
        }
        #pragma unroll
        for (int j = 0; j < 8; j++) sum += v8[j];
    }
    __shared__ float wsum[2], wvar[2];
    #pragma unroll
    for (int o = 32; o > 0; o >>= 1) sum += __shfl_xor(sum, o);
    if ((tid & 63) == 0) wsum[tid >> 6] = sum;
    __syncthreads();
    float mean = (wsum[0] + wsum[1]) * (1.0f / H_);
    float vs = 0.f;
    if (act) {
        for (int j = 0; j < 8; j++) { float d = v8[j] - mean; vs += d * d; }
    }
    #pragma unroll
    for (int o = 32; o > 0; o >>= 1) vs += __shfl_xor(vs, o);
    if ((tid & 63) == 0) wvar[tid >> 6] = vs;
    __syncthreads();
    float inv = 1.0f / sqrtf((wvar[0] + wvar[1]) * (1.0f / H_) + 1e-12f);
    if (act) {
        float o8[8];
        #pragma unroll
        for (int j = 0; j < 8; j++) o8[j] = (v8[j] - mean) * inv * g[idx + j] + bb[idx + j];
        us8 h, l; pack8(o8, h, l);
        unsigned short* p = out_pk + ((size_t)tok * 96 + tid) * 16;
        *reinterpret_cast<us8*>(p) = h;
        *reinterpret_cast<us8*>(p + 8) = l;
    }
}

// ================= residual + LN (in-place packed) =================
__global__ __launch_bounds__(128) void k_res_ln(
    const float* __restrict__ x, const float* __restrict__ g, const float* __restrict__ bb,
    unsigned short* __restrict__ h_pk)
{
    int tok = blockIdx.x;
    int tid = threadIdx.x;
    bool act = tid < 96;
    int idx = tid * 8;
    float v8[8];
    float sum = 0.f;
    unsigned short* p = h_pk + ((size_t)tok * 96 + tid) * 16;
    if (act) {
        const float4* x4 = reinterpret_cast<const float4*>(x + (size_t)tok * H_ + idx);
        us8 hi = *reinterpret_cast<const us8*>(p);
        us8 lo = *reinterpret_cast<const us8*>(p + 8);
        float4 a0 = x4[0], a1 = x4[1];
        float xs[8] = {a0.x, a0.y, a0.z, a0.w, a1.x, a1.y, a1.z, a1.w};
        #pragma unroll
        for (int j = 0; j < 8; j++) {
            v8[j] = xs[j] + bf2f(hi[j]) + bf2f(lo[j]);
            sum += v8[j];
        }
    }
    __shared__ float wsum[2], wvar[2];
    #pragma unroll
    for (int o = 32; o > 0; o >>= 1) sum += __shfl_xor(sum, o);
    if ((tid & 63) == 0) wsum[tid >> 6] = sum;
    __syncthreads();
    float mean = (wsum[0] + wsum[1]) * (1.0f / H_);
    float vs = 0.f;
    if (act) {
        for (int j = 0; j < 8; j++) { float d = v8[j] - mean; vs += d * d; }
    }
    #pragma unroll
    for (int o = 32; o > 0; o >>= 1) vs += __shfl_xor(vs, o);
    if ((tid & 63) == 0) wvar[tid >> 6] = vs;
    __syncthreads();
    float inv = 1.0f / sqrtf((wvar[0] + wvar[1]) * (1.0f / H_) + 1e-12f);
    if (act) {
        float o8[8];
        #pragma unroll
        for (int j = 0; j < 8; j++) o8[j] = (v8[j] - mean) * inv * g[idx + j] + bb[idx + j];
        us8 h, l; pack8(o8, h, l);
        *reinterpret_cast<us8*>(p) = h;
        *reinterpret_cast<us8*>(p + 8) = l;
    }
}

// ================= packed MFMA GEMM: 3-buffer, ONE barrier/K-step, counted vmcnt =================
__global__ __launch_bounds__(256) void k_gemm_pk(
    const unsigned short* __restrict__ A, const unsigned short* __restrict__ Wp,
    const float* __restrict__ bias,
    float* __restrict__ C0, float* __restrict__ C1, float* __restrict__ C2, int cpb,
    unsigned short* __restrict__ Cpk,
    int M, int N, int K, int act, int cbx)
{
    constexpr int BUFSZ = 24576;               // A 16KB + B 8KB
    __shared__ char smem[3 * BUFSZ];
    unsigned smb = (unsigned)(size_t)(void*)smem;

    int id = blockIdx.x;
    int xcd = id & 7;
    int rr = id >> 3;
    int by = (xcd >> 1) * 8 + rr / cbx;
    int bx = (xcd & 1) * cbx + rr % cbx;
    int m0 = by << 7, n0 = bx << 6;
    int Kb = K >> 3;
    int nst = Kb >> 2;
    int rowbytes = Kb * 32;

    int tid = threadIdx.x;
    int lane = tid & 63, wid = tid >> 6;
    int wm = wid >> 1, wn = wid & 1;
    int fr = lane & 15, fq = lane >> 4;

    f4 acc[4][2];
    #pragma unroll
    for (int i = 0; i < 4; i++)
        #pragma unroll
        for (int j = 0; j < 2; j++) acc[i][j] = (f4){0.f, 0.f, 0.f, 0.f};

    const char* agp[4];
    const char* bgp[2];
    #pragma unroll
    for (int i = 0; i < 4; i++) {
        int d = i * 4096 + tid * 16;
        int row = d >> 7;
        int colp = (d & 127) ^ ((row & 7) << 4);
        agp[i] = (const char*)A + (size_t)(m0 + row) * rowbytes + colp;
    }
    #pragma unroll
    for (int i = 0; i < 2; i++) {
        int d = i * 4096 + tid * 16;
        int row = d >> 7;
        int colp = (d & 127) ^ ((row & 7) << 4);
        bgp[i] = (const char*)Wp + (size_t)(n0 + row) * rowbytes + colp;
    }

    int afo[4], bfo[2];
    #pragma unroll
    for (int mi = 0; mi < 4; mi++) {
        int r = wm * 64 + mi * 16 + fr;
        afo[mi] = r * 128 + ((fq * 32) ^ ((r & 7) << 4));
    }
    #pragma unroll
    for (int ni = 0; ni < 2; ni++) {
        int rb = wn * 32 + ni * 16 + fr;
        bfo[ni] = 16384 + rb * 128 + ((fq * 32) ^ ((rb & 7) << 4));
    }

    auto issue = [&](int ks, unsigned boff) {
        size_t ko = (size_t)ks * 128;
        #pragma unroll
        for (int i = 0; i < 4; i++)
            __builtin_amdgcn_global_load_lds((const AS1 void*)(size_t)(agp[i] + ko),
                (AS3 void*)(unsigned)(smb + boff + i * 4096 + wid * 1024), 16, 0, 0);
        #pragma unroll
        for (int i = 0; i < 2; i++)
            __builtin_amdgcn_global_load_lds((const AS1 void*)(size_t)(bgp[i] + ko),
                (AS3 void*)(unsigned)(smb + boff + 16384 + i * 4096 + wid * 1024), 16, 0, 0);
    };

    issue(0, 0);
    if (nst > 1) issue(1, BUFSZ);
    unsigned c0 = 0, c1 = BUFSZ, c2 = 2 * BUFSZ;

    for (int ks = 0; ks < nst; ks++) {
        if (ks + 1 < nst) asm volatile("s_waitcnt vmcnt(6)" ::: "memory");
        else              asm volatile("s_waitcnt vmcnt(0)" ::: "memory");
        __builtin_amdgcn_s_barrier();
        __builtin_amdgcn_sched_barrier(0);
        if (ks + 2 < nst) issue(ks + 2, c2);

        const char* cbp = smem + c0;
        bfrag ah[4], al[4], bh[2], bl[2];
        #pragma unroll
        for (int mi = 0; mi < 4; mi++) {
            ah[mi] = *reinterpret_cast<const bfrag*>(cbp + afo[mi]);
            al[mi] = *reinterpret_cast<const bfrag*>(cbp + (afo[mi] ^ 16));
        }
        #pragma unroll
        for (int ni = 0; ni < 2; ni++) {
            bh[ni] = *reinterpret_cast<const bfrag*>(cbp + bfo[ni]);
            bl[ni] = *reinterpret_cast<const bfrag*>(cbp + (bfo[ni] ^ 16));
        }
        #pragma unroll
        for (int mi = 0; mi < 4; mi++) {
            #pragma unroll
            for (int ni = 0; ni < 2; ni++) {
                acc[mi][ni] = __builtin_amdgcn_mfma_f32_16x16x32_bf16(ah[mi], bh[ni], acc[mi][ni], 0, 0, 0);
                acc[mi][ni] = __builtin_amdgcn_mfma_f32_16x16x32_bf16(ah[mi], bl[ni], acc[mi][ni], 0, 0, 0);
                acc[mi][ni] = __builtin_amdgcn_mfma_f32_16x16x32_bf16(al[mi], bh[ni], acc[mi][ni], 0, 0, 0);
            }
        }
        unsigned t = c0; c0 = c1; c1 = c2; c2 = t;
    }

    if (act == 0) {
        #pragma unroll
        for (int mi = 0; mi < 4; mi++) {
            #pragma unroll
            for (int ni = 0; ni < 2; ni++) {
                int col = n0 + wn * 32 + ni * 16 + fr;
                float bv = bias[col];
                int buf = col / cpb;
                float* Cp = (buf == 0) ? C0 : (buf == 1) ? C1 : C2;
                int cc = col - buf * cpb;
                #pragma unroll
                for (int r = 0; r < 4; r++) {
                    int row = m0 + wm * 64 + mi * 16 + fq * 4 + r;
                    Cp[(size_t)row * cpb + cc] = acc[mi][ni][r] + bv;
                }
            }
        }
    } else {
        __syncthreads();
        float* ebuf = (float*)(smem + wid * 2432);
        int Nb = N >> 3;
        #pragma unroll
        for (int mi = 0; mi < 4; mi++) {
            #pragma unroll
            for (int ni = 0; ni < 2; ni++) {
                int col = n0 + wn * 32 + ni * 16 + fr;
                float bv = bias[col];
                #pragma unroll
                for (int r = 0; r < 4; r++) {
                    float v = acc[mi][ni][r] + bv;
                    v = 0.5f * v * (1.0f + erff(v * 0.70710678118654752f));
                    ebuf[(fq * 4 + r) * 38 + ni * 16 + fr] = v;
                }
            }
            int row16 = lane >> 2, kb = lane & 3;
            float v8[8];
            #pragma unroll
            for (int j = 0; j < 8; j++) v8[j] = ebuf[row16 * 38 + kb * 8 + j];
            us8 h, l; pack8(v8, h, l);
            int grow = m0 + wm * 64 + mi * 16 + row16;
            int gcb = ((n0 + wn * 32) >> 3) + kb;
            unsigned short* p = Cpk + ((size_t)grow * Nb + gcb) * 16;
            *reinterpret_cast<us8*>(p) = h;
            *reinterpret_cast<us8*>(p + 8) = l;
        }
    }
}

// ================= fused flash attention (exp2-domain online softmax) =================
#define SM_KH 0
#define SM_KL 5632
#define SM_VH 11264
#define SM_VL 16384
#define SM_PH 21504
#define SM_PL 26624
__global__ __launch_bounds__(256) void k_attn_fused(
    const float* __restrict__ Q, const float* __restrict__ Kb,
    const float* __restrict__ V, const int* __restrict__ amask,
    unsigned short* __restrict__ ctx_pk)
{
    __shared__ char smem[31744];
    unsigned short* KhS = (unsigned short*)(smem + SM_KH);
    unsigned short* KlS = (unsigned short*)(smem + SM_KL);
    unsigned short* VhS = (unsigned short*)(smem + SM_VH);
    unsigned short* VlS = (unsigned short*)(smem + SM_VL);
    unsigned short* PhS = (unsigned short*)(smem + SM_PH);
    unsigned short* PlS = (unsigned short*)(smem + SM_PL);

    int idx = blockIdx.x;
    int qt = idx & 3;
    int hd = (idx >> 2) % NH_;
    int b = idx / (4 * NH_);
    int tid = threadIdx.x;
    int lane = tid & 63, wid = tid >> 6;
    int fr = lane & 15, fq = lane >> 4;

    int q0 = qt * 64 + wid * 16;

    bfrag qh[2], ql[2];
    {
        const float* qbase = Q + ((size_t)(b * S_ + q0 + fr)) * H_ + hd * DH_;
        #pragma unroll
        for (int ks = 0; ks < 2; ks++) {
            const float4* p = reinterpret_cast<const float4*>(qbase + ks * 32 + fq * 8);
            float4 v0 = p[0], v1 = p[1];
            float vv[8] = {v0.x, v0.y, v0.z, v0.w, v1.x, v1.y, v1.z, v1.w};
            #pragma unroll
            for (int j = 0; j < 8; j++) {
                unsigned short h = f2bf(vv[j]);
                qh[ks][j] = (short)h;
                ql[ks][j] = (short)f2bf(vv[j] - bf2f(h));
            }
        }
    }

    f4 o[4];
    #pragma unroll
    for (int i = 0; i < 4; i++) o[i] = (f4){0.f, 0.f, 0.f, 0.f};
    float m[4], l[4];
    #pragma unroll
    for (int r = 0; r < 4; r++) { m[r] = -3e38f; l[r] = 0.f; }

    int kvrow = tid >> 3;
    int dbase = (tid & 7) * 8;

    const float SCL2 = 0.125f * LOG2E_;
    const float MB2  = -1e9f * LOG2E_;

    for (int t = 0; t < 8; t++) {
        {
            const float* src = Kb + ((size_t)(b * S_ + t * 32 + kvrow)) * H_ + hd * DH_ + dbase;
            float4 a4 = reinterpret_cast<const float4*>(src)[0];
            float4 b4 = reinterpret_cast<const float4*>(src)[1];
            float vv[8] = {a4.x, a4.y, a4.z, a4.w, b4.x, b4.y, b4.z, b4.w};
            us8 h, l2;
            #pragma unroll
            for (int j = 0; j < 8; j++) {
                unsigned short hh = f2bf(vv[j]);
                h[j] = hh; l2[j] = f2bf(vv[j] - bf2f(hh));
            }
            *reinterpret_cast<us8*>(&KhS[kvrow * 88 + dbase]) = h;
            *reinterpret_cast<us8*>(&KlS[kvrow * 88 + dbase]) = l2;
        }
        {
            const float* src = V + ((size_t)(b * S_ + t * 32 + kvrow)) * H_ + hd * DH_ + dbase;
            float4 a4 = reinterpret_cast<const float4*>(src)[0];
            float4 b4 = reinterpret_cast<const float4*>(src)[1];
            float vv[8] = {a4.x, a4.y, a4.z, a4.w, b4.x, b4.y, b4.z, b4.w};
            #pragma unroll
            for (int j = 0; j < 8; j++) {
                unsigned short h = f2bf(vv[j]);
                VhS[(dbase + j) * 40 + kvrow] = h;
                VlS[(dbase + j) * 40 + kvrow] = f2bf(vv[j] - bf2f(h));
            }
        }
        __syncthreads();

        f4 s0 = (f4){0.f,0.f,0.f,0.f}, s1 = (f4){0.f,0.f,0.f,0.f};
        #pragma unroll
        for (int ks = 0; ks < 2; ks++) {
            bfrag kbh0 = *reinterpret_cast<const bfrag*>(&KhS[fr * 88 + ks * 32 + fq * 8]);
            bfrag kbl0 = *reinterpret_cast<const bfrag*>(&KlS[fr * 88 + ks * 32 + fq * 8]);
            bfrag kbh1 = *reinterpret_cast<const bfrag*>(&KhS[(16 + fr) * 88 + ks * 32 + fq * 8]);
            bfrag kbl1 = *reinterpret_cast<const bfrag*>(&KlS[(16 + fr) * 88 + ks * 32 + fq * 8]);
            s0 = __builtin_amdgcn_mfma_f32_16x16x32_bf16(qh[ks], kbh0, s0, 0, 0, 0);
            s0 = __builtin_amdgcn_mfma_f32_16x16x32_bf16(qh[ks], kbl0, s0, 0, 0, 0);
            s0 = __builtin_amdgcn_mfma_f32_16x16x32_bf16(ql[ks], kbh0, s0, 0, 0, 0);
            s1 = __builtin_amdgcn_mfma_f32_16x16x32_bf16(qh[ks], kbh1, s1, 0, 0, 0);
            s1 = __builtin_amdgcn_mfma_f32_16x16x32_bf16(qh[ks], kbl1, s1, 0, 0, 0);
            s1 = __builtin_amdgcn_mfma_f32_16x16x32_bf16(ql[ks], kbh1, s1, 0, 0, 0);
        }

        float cb0 = (amask[b * S_ + t * 32 + fr] == 0) ? MB2 : 0.f;
        float cb1 = (amask[b * S_ + t * 32 + 16 + fr] == 0) ? MB2 : 0.f;
        float sc0[4], sc1[4], fct[4], pr0[4], pr1[4];
        #pragma unroll
        for (int r = 0; r < 4; r++) {
            sc0[r] = s0[r] * SCL2 + cb0;
            sc1[r] = s1[r] * SCL2 + cb1;
            float tm = fmaxf(sc0[r], sc1[r]);
            #pragma unroll
            for (int od = 1; od < 16; od <<= 1) tm = fmaxf(tm, __shfl_xor(tm, od));
            float mn = fmaxf(m[r], tm);
            fct[r] = exp2f(m[r] - mn);
            pr0[r] = exp2f(sc0[r] - mn);
            pr1[r] = exp2f(sc1[r] - mn);
            float rs = pr0[r] + pr1[r];
            #pragma unroll
            for (int od = 1; od < 16; od <<= 1) rs += __shfl_xor(rs, od);
            l[r] = l[r] * fct[r] + rs;
            m[r] = mn;
        }
        #pragma unroll
        for (int ci = 0; ci < 4; ci++)
            #pragma unroll
            for (int r = 0; r < 4; r++) o[ci][r] *= fct[r];

        #pragma unroll
        for (int r = 0; r < 4; r++) {
            int row = fq * 4 + r;
            unsigned short h0 = f2bf(pr0[r]);
            PhS[wid * 640 + row * 40 + fr] = h0;
            PlS[wid * 640 + row * 40 + fr] = f2bf(pr0[r] - bf2f(h0));
            unsigned short h1 = f2bf(pr1[r]);
            PhS[wid * 640 + row * 40 + 16 + fr] = h1;
            PlS[wid * 640 + row * 40 + 16 + fr] = f2bf(pr1[r] - bf2f(h1));
        }

        bfrag pah = *reinterpret_cast<const bfrag*>(&PhS[wid * 640 + fr * 40 + fq * 8]);
        bfrag pal = *reinterpret_cast<const bfrag*>(&PlS[wid * 640 + fr * 40 + fq * 8]);
        #pragma unroll
        for (int ci = 0; ci < 4; ci++) {
            bfrag vbh = *reinterpret_cast<const bfrag*>(&VhS[(ci * 16 + fr) * 40 + fq * 8]);
            bfrag vbl = *reinterpret_cast<const bfrag*>(&VlS[(ci * 16 + fr) * 40 + fq * 8]);
            o[ci] = __builtin_amdgcn_mfma_f32_16x16x32_bf16(pah, vbh, o[ci], 0, 0, 0);
            o[ci] = __builtin_amdgcn_mfma_f32_16x16x32_bf16(pah, vbl, o[ci], 0, 0, 0);
            o[ci] = __builtin_amdgcn_mfma_f32_16x16x32_bf16(pal, vbh, o[ci], 0, 0, 0);
        }
        __syncthreads();
    }

    __syncthreads();
    float* eb = (float*)smem + wid * 1088;
    #pragma unroll
    for (int r = 0; r < 4; r++) {
        float inv = 1.0f / l[r];
        #pragma unroll
        for (int ci = 0; ci < 4; ci++)
            eb[(fq * 4 + r) * 68 + ci * 16 + fr] = o[ci][r] * inv;
    }
    __syncthreads();
    #pragma unroll
    for (int e = 0; e < 2; e++) {
        int item = lane * 2 + e;
        int row16 = item >> 3, kb = item & 7;
        float v8[8];
        #pragma unroll
        for (int j = 0; j < 8; j++) v8[j] = eb[row16 * 68 + kb * 8 + j];
        us8 h, l2; pack8(v8, h, l2);
        int grow = b * S_ + q0 + row16;
        int gcb = hd * 8 + kb;
        unsigned short* p = ctx_pk + ((size_t)grow * 96 + gcb) * 16;
        *reinterpret_cast<us8*>(p) = h;
        *reinterpret_cast<us8*>(p + 8) = l2;
    }
}

// ================= classifier (packed h) =================
__global__ __launch_bounds__(64) void k_classifier(
    const unsigned short* __restrict__ Hpk, const float* __restrict__ Wc,
    const float* __restrict__ bc, float* __restrict__ logits)
{
    int tok = blockIdx.x;
    int lane = threadIdx.x;
    float acc[T_];
    #pragma unroll
    for (int j = 0; j < T_; j++) acc[j] = 0.f;
    for (int kb = lane; kb < 96; kb += 64) {
        const unsigned short* p = Hpk + ((size_t)tok * 96 + kb) * 16;
        us8 hi = *reinterpret_cast<const us8*>(p);
        us8 lo = *reinterpret_cast<const us8*>(p + 8);
        #pragma unroll
        for (int e = 0; e < 8; e++) {
            float hv = bf2f(hi[e]) + bf2f(lo[e]);
            const float* wr = Wc + (size_t)(kb * 8 + e) * T_;
            #pragma unroll
            for (int j = 0; j < T_; j++) acc[j] = fmaf(hv, wr[j], acc[j]);
        }
    }
    #pragma unroll
    for (int j = 0; j < T_; j++) {
        float v = acc[j];
        for (int o = 32; o > 0; o >>= 1) v += __shfl_down(v, o);
        if (lane == 0) logits[(size_t)tok * T_ + j] = v + bc[j];
    }
}

// ================= fused CRF + Viterbi (drop-max LSE, renorm/8, 8-deep em ring) =================
__global__ __launch_bounds__(256) void k_crf_vit(
    const float* __restrict__ logits, const int* __restrict__ amask,
    const int* __restrict__ labels, const float* __restrict__ start,
    const float* __restrict__ endv, const float* __restrict__ trans,
    float* __restrict__ out)
{
    int blk = blockIdx.x;
    int tid = threadIdx.x;
    if (blk == 0) {
        __shared__ float res[B_];
        int lane = tid & 63;
        int bb = (tid >> 6) * 4 + (lane >> 4);
        int sj = lane & 15;
        int lb = lane & 48;

        int cnt = 0;
        for (int s = sj; s < S_; s += 16) cnt += amask[bb * S_ + s];
        #pragma unroll
        for (int o = 8; o > 0; o >>= 1) cnt += __shfl_xor(cnt, o);
        int len = cnt;
        int lim = len - 1;

        float num = 0.f;
        for (int s = 2 + sj; s < S_; s += 16) {
            if (s < lim) {
                int tp = labels[bb * S_ + s - 1];
                int tc = labels[bb * S_ + s];
                num += trans[tp * T_ + tc] + logits[((size_t)(bb * S_ + s)) * T_ + tc];
            }
        }
        #pragma unroll
        for (int o = 8; o > 0; o >>= 1) num += __shfl_xor(num, o);
        int tg1 = labels[bb * S_ + 1];
        num += start[tg1] + logits[((size_t)(bb * S_ + 1)) * T_ + tg1];
        num += endv[labels[bb * S_ + (len - 2)]];

        float tc9[T_];
        #pragma unroll
        for (int i = 0; i < T_; i++) tc9[i] = (sj < T_) ? trans[i * T_ + sj] * LOG2E_ : 0.f;
        float score = (sj < T_) ? (start[sj] + logits[((size_t)(bb * S_ + 1)) * T_ + sj]) * LOG2E_ : 0.f;
        float base = 0.f;
        const float* embase = logits + (size_t)bb * S_ * T_ + sj;
        float emb[8];
        #pragma unroll
        for (int c = 0; c < 8; c++) emb[c] = (sj < T_) ? embase[(2 + c) * T_] : 0.f;
        for (int s0 = 2; s0 < S_; s0 += 8) {
            #pragma unroll
            for (int c = 0; c < 8; c++) {
                int s = s0 + c;
                if (s < S_) {
                    float em = emb[c];
                    emb[c] = (sj < T_ && s + 8 < S_) ? embase[(size_t)(s + 8) * T_] : 0.f;
                    float si[T_];
                    #pragma unroll
                    for (int i = 0; i < T_; i++) si[i] = __shfl(score, lb + i);
                    float e2[T_];
                    #pragma unroll
                    for (int i = 0; i < T_; i++) e2[i] = exp2f(si[i] + tc9[i]);
                    float s01 = e2[0] + e2[1], s23 = e2[2] + e2[3];
                    float s45 = e2[4] + e2[5], s67 = e2[6] + e2[7];
                    float sum = ((s01 + s23) + (s45 + s67)) + e2[8];
                    float nsc = fmaf(em, LOG2E_, log2f(sum));
                    if (s < lim) score = nsc;
                }
            }
            float sh = __shfl(score, lb);
            score -= sh;
            base += sh;
        }
        float se = (sj < T_) ? score + endv[sj] * LOG2E_ : -1e30f;
        float fi[T_];
        #pragma unroll
        for (int i = 0; i < T_; i++) fi[i] = __shfl(se, lb + i);
        if (sj == 0) {
            float mx = -1e30f;
            #pragma unroll
            for (int i = 0; i < T_; i++) mx = fmaxf(mx, fi[i]);
            float sum = 0.f;
            #pragma unroll
            for (int i = 0; i < T_; i++) sum += exp2f(fi[i] - mx);
            res[bb] = (base + mx + log2f(sum)) * LN2_ - num;
        }
        __syncthreads();
        if (tid == 0) {
            float tot = 0.f;
            #pragma unroll
            for (int i = 0; i < B_; i++) tot += res[i];
            out[0] = tot;
        }
    } else {
        if (tid >= 64) return;
        int b = blk - 1;
        int j = tid;
        float* tags_out = out + 1;
        __shared__ unsigned char hist[S_ - 1][T_];
        float tc9[T_];
        #pragma unroll
        for (int i = 0; i < T_; i++) tc9[i] = (j < T_) ? trans[i * T_ + j] : 0.f;
        float score = (j < T_) ? start[j] + logits[((size_t)(b * S_)) * T_ + j] : -1e30f;
        const float* embase = logits + (size_t)b * S_ * T_ + j;
        float emb[8];
        #pragma unroll
        for (int c = 0; c < 8; c++) emb[c] = (j < T_) ? embase[(1 + c) * T_] : 0.f;
        for (int t0 = 1; t0 < S_; t0 += 8) {
            #pragma unroll
            for (int c = 0; c < 8; c++) {
                int t = t0 + c;
                if (t < S_) {
                    float em = emb[c];
                    emb[c] = (j < T_ && t + 8 < S_) ? embase[(size_t)(t + 8) * T_] : 0.f;
                    float si[T_];
                    #pragma unroll
                    for (int i = 0; i < T_; i++) si[i] = __shfl(score, i);
                    float cv[T_];
                    #pragma unroll
                    for (int i = 0; i < T_; i++) cv[i] = si[i] + tc9[i];
                    float v01 = cv[0]; int i01 = 0; if (cv[1] > v01) { v01 = cv[1]; i01 = 1; }
                    float v23 = cv[2]; int i23 = 2; if (cv[3] > v23) { v23 = cv[3]; i23 = 3; }
                    float v45 = cv[4]; int i45 = 4; if (cv[5] > v45) { v45 = cv[5]; i45 = 5; }
                    float v67 = cv[6]; int i67 = 6; if (cv[7] > v67) { v67 = cv[7]; i67 = 7; }
                    float v03 = v01; int i03 = i01; if (v23 > v03) { v03 = v23; i03 = i23; }
                    float v47 = v45; int i47 = i45; if (v67 > v47) { v47 = v67; i47 = i67; }
                    float v07 = v03; int i07 = i03; if (v47 > v07) { v07 = v47; i07 = i47; }
                    float best = v07; int bi = i07; if (cv[8] > best) { best = cv[8]; bi = 8; }
                    if (j < T_) {
                        hist[t - 1][j] = (unsigned char)bi;
                        score = best + em;
                    }
                }
            }
        }
        float se = (j < T_) ? score + endv[j] : -1e30f;
        float fi[T_];
        #pragma unroll
        for (int i = 0; i < T_; i++) fi[i] = __shfl(se, i);
        if (j == 0) {
            float best = -1e30f; int last = 0;
            #pragma unroll
            for (int i = 0; i < T_; i++) if (fi[i] > best) { best = fi[i]; last = i; }
            tags_out[b * S_ + (S_ - 1)] = (float)last;
            int cur = last;
            for (int t = S_ - 2; t >= 0; t--) {
                cur = hist[t][cur];
                tags_out[b * S_ + t] = (float)cur;
            }
        }
    }
}

// ================= driver =================
extern "C" void kernel_launch(void* const* d_in, const int* in_sizes, int n_in,
                              void* d_out, int out_size, void* d_ws, size_t ws_size,
                              hipStream_t stream)
{
    const int*   input_ids = (const int*)d_in[0];
    const int*   amask     = (const int*)d_in[1];
    const int*   labels    = (const int*)d_in[2];
    const float* word_emb  = (const float*)d_in[3];
    const float* pos_emb   = (const float*)d_in[4];
    const float* type_emb  = (const float*)d_in[5];
    const float* emb_g     = (const float*)d_in[6];
    const float* emb_b     = (const float*)d_in[7];
    const float* lWq = (const float*)d_in[8];
    const float* lbq = (const float*)d_in[9];
    const float* lWk = (const float*)d_in[10];
    const float* lbk = (const float*)d_in[11];
    const float* lWv = (const float*)d_in[12];
    const float* lbv = (const float*)d_in[13];
    const float* lWo = (const float*)d_in[14];
    const float* lbo = (const float*)d_in[15];
    const float* lg1 = (const float*)d_in[16];
    const float* lb1 = (const float*)d_in[17];
    const float* lWi = (const float*)d_in[18];
    const float* lbi = (const float*)d_in[19];
    const float* lWf = (const float*)d_in[20];
    const float* lbf = (const float*)d_in[21];
    const float* lg2 = (const float*)d_in[22];
    const float* lb2 = (const float*)d_in[23];
    const float* cls_W = (const float*)d_in[24];
    const float* cls_b = (const float*)d_in[25];
    const float* crf_start = (const float*)d_in[26];
    const float* crf_end   = (const float*)d_in[27];
    const float* crf_trans = (const float*)d_in[28];

    float* out = (float*)d_out;
    float* ws = (float*)d_ws;

    const size_t NH32 = (size_t)NTOK * H_;
    float* h_pk_f  = ws + NH32;
    float* q       = ws + 2 * NH32;
    float* kbuf    = ws + 3 * NH32;
    float* v       = ws + 4 * NH32;
    float* ctxpk_f = ws + 5 * NH32;
    float* tmp     = ws + 6 * NH32;
    float* Wpk_f   = ws + 7 * NH32;
    float* qkvbias = Wpk_f + 7077888;
    float* logits  = qkvbias + 3 * H_;

    unsigned short* h_pk   = (unsigned short*)h_pk_f;
    unsigned short* ctx_pk = (unsigned short*)ctxpk_f;
    unsigned short* Wpk    = (unsigned short*)Wpk_f;
    unsigned short* big_pk = (unsigned short*)q;

    k_embed_ln<<<NTOK, 128, 0, stream>>>(input_ids, word_emb, pos_emb, type_emb, emb_g, emb_b, h_pk);

    const size_t WOFF_O = 221184, WOFF_I = 294912, WOFF_F = 589824;

    for (int l = 0; l < L_; l++) {
        k_conv_w<<<1728, 256, 0, stream>>>(
            lWq + (size_t)l * H_ * H_, lWk + (size_t)l * H_ * H_,
            lWv + (size_t)l * H_ * H_, lWo + (size_t)l * H_ * H_,
            lWi + (size_t)l * H_ * FF_, lWf + (size_t)l * FF_ * H_,
            lbq + (size_t)l * H_, lbk + (size_t)l * H_, lbv + (size_t)l * H_,
            qkvbias, Wpk);

        // fused QKV: N = 2304 -> 32x36 blocks, chunk 8x18
        k_gemm_pk<<<1152, 256, 0, stream>>>(h_pk, Wpk, qkvbias,
            q, kbuf, v, H_, nullptr, NTOK, 3 * H_, H_, 0, 18);

        k_attn_fused<<<B_ * NH_ * 4, 256, 0, stream>>>(q, kbuf, v, amask, ctx_pk);

        // attn-out: N = 768 -> 32x12 blocks, chunk 8x6
        k_gemm_pk<<<384, 256, 0, stream>>>(ctx_pk, Wpk + WOFF_O * 16, lbo + (size_t)l * H_,
            tmp, tmp, tmp, H_, nullptr, NTOK, H_, H_, 0, 6);

        k_res_ln<<<NTOK, 128, 0, stream>>>(tmp, lg1 + (size_t)l * H_, lb1 + (size_t)l * H_, h_pk);

        // FF1: N = 3072 -> 32x48 blocks, chunk 8x24
        k_gemm_pk<<<1536, 256, 0, stream>>>(h_pk, Wpk + WOFF_I * 16, lbi + (size_t)l * FF_,
            tmp, tmp, tmp, FF_, big_pk, NTOK, FF_, H_, 1, 24);

        // FF2: N = 768, K = 3072 -> 32x12 blocks, chunk 8x6
        k_gemm_pk<<<384, 256, 0, stream>>>(big_pk, Wpk + WOFF_F * 16, lbf + (size_t)l * H_,
            tmp, tmp, tmp, H_, nullptr, NTOK, H_, FF_, 0, 6);

        k_res_ln<<<NTOK, 128, 0, stream>>>(tmp, lg2 + (size_t)l * H_, lb2 + (size_t)l * H_, h_pk);
    }

    k_classifier<<<NTOK, 64, 0, stream>>>(h_pk, cls_W, cls_b, logits);
    k_crf_vit<<<1 + B_, 256, 0, stream>>>(logits, amask, labels, crf_start, crf_end, crf_trans, out);
}

// Round 22
// 3544.104 us; speedup vs baseline: 1.0026x; 1.0026x over previous
//
#include <hip/hip_runtime.h>

#define B_ 16
#define S_ 256
#define H_ 768
#define NH_ 12
#define DH_ 64
#define L_ 12
#define FF_ 3072
#define T_ 9
#define NTOK (B_*S_)

#define AS1 __attribute__((address_space(1)))
#define AS3 __attribute__((address_space(3)))

typedef __attribute__((ext_vector_type(8))) short bfrag;
typedef __attribute__((ext_vector_type(8))) unsigned short us8;
typedef __attribute__((ext_vector_type(4))) float f4;

#define LOG2E_ 1.4426950408889634f
#define LN2_   0.6931471805599453f

__device__ inline unsigned short f2bf(float x) {
    unsigned u = __builtin_bit_cast(unsigned, x);
    return (unsigned short)((u + 0x7fffu + ((u >> 16) & 1u)) >> 16);
}
__device__ inline float bf2f(unsigned short h) {
    unsigned u = ((unsigned)h) << 16;
    return __builtin_bit_cast(float, u);
}
__device__ inline void pack8(const float* v, us8& h, us8& l) {
    #pragma unroll
    for (int j = 0; j < 8; j++) {
        unsigned short hh = f2bf(v[j]);
        h[j] = hh;
        l[j] = f2bf(v[j] - bf2f(hh));
    }
}

// ================= weight convert =================
__global__ __launch_bounds__(256) void k_conv_w(
    const float* __restrict__ Wq, const float* __restrict__ Wk,
    const float* __restrict__ Wv, const float* __restrict__ Wo,
    const float* __restrict__ Wi, const float* __restrict__ Wf,
    const float* __restrict__ bq, const float* __restrict__ bk, const float* __restrict__ bv,
    float* __restrict__ qkvbias, unsigned short* __restrict__ Wpk)
{
    int bid = blockIdx.x;
    int tid = threadIdx.x;
    if (bid == 0) {
        for (int i = tid; i < 3 * H_; i += 256)
            qkvbias[i] = (i < H_) ? bq[i] : (i < 2 * H_) ? bk[i - H_] : bv[i - 2 * H_];
    }
    const float* src; int Kd, Nd; size_t doff; int t;
    if (bid < 576)       { int m = bid / 144; src = (m == 0) ? Wq : (m == 1) ? Wk : (m == 2) ? Wv : Wo;
                           Kd = H_; Nd = H_; doff = (size_t)m * 73728; t = bid % 144; }
    else if (bid < 1152) { src = Wi; Kd = H_; Nd = FF_; doff = 294912; t = bid - 576; }
    else                 { src = Wf; Kd = FF_; Nd = H_; doff = 589824; t = bid - 1152; }
    int ntn = Nd / 64;
    int tk = t / ntn, tn = t % ntn;
    int k0 = tk * 64, n0 = tn * 64;
    __shared__ float tile[64][65];
    int r = tid >> 6, c = tid & 63;
    #pragma unroll
    for (int i = 0; i < 16; i++)
        tile[r + i * 4][c] = src[(size_t)(k0 + r + i * 4) * Nd + n0 + c];
    __syncthreads();
    #pragma unroll
    for (int e = 0; e < 2; e++) {
        int item = tid * 2 + e;
        int nl = item >> 3, kb = item & 7;
        float v8[8];
        #pragma unroll
        for (int j = 0; j < 8; j++) v8[j] = tile[kb * 8 + j][nl];
        us8 h, l; pack8(v8, h, l);
        unsigned short* p = Wpk + (doff + (size_t)(n0 + nl) * (Kd / 8) + (k0 / 8 + kb)) * 16;
        *reinterpret_cast<us8*>(p) = h;
        *reinterpret_cast<us8*>(p + 8) = l;
    }
}

// ================= embedding + LN (packed only) =================
__global__ __launch_bounds__(128) void k_embed_ln(
    const int* __restrict__ ids, const float* __restrict__ wemb,
    const float* __restrict__ pemb, const float* __restrict__ temb,
    const float* __restrict__ g, const float* __restrict__ bb,
    unsigned short* __restrict__ out_pk)
{
    int tok = blockIdx.x;
    int s = tok & (S_ - 1);
    int id = ids[tok];
    int tid = threadIdx.x;
    bool act = tid < 96;
    int idx = tid * 8;
    float v8[8];
    float sum = 0.f;
    if (act) {
        const float4* w4 = reinterpret_cast<const float4*>(wemb + (size_t)id * H_ + idx);
        const float4* p4 = reinterpret_cast<const float4*>(pemb + (size_t)s * H_ + idx);
        const float4* t4 = reinterpret_cast<const float4*>(temb + idx);
        #pragma unroll
        for (int q = 0; q < 2; q++) {
            float4 a = w4[q], b = p4[q], c = t4[q];
            v8[q*4+0] = a.x + b.x + c.x; v8[q*4+1] = a.y + b.y + c.y;
            v8[q*4+2] = a.z + b.z + c.z; v8[q*4+3] = a.w + b.w + c.w;
        }
        #pragma unroll
        for (int j = 0; j < 8; j++) sum += v8[j];
    }
    __shared__ float wsum[2], wvar[2];
    #pragma unroll
    for (int o = 32; o > 0; o >>= 1) sum += __shfl_xor(sum, o);
    if ((tid & 63) == 0) wsum[tid >> 6] = sum;
    __syncthreads();
    float mean = (wsum[0] + wsum[1]) * (1.0f / H_);
    float vs = 0.f;
    if (act) {
        for (int j = 0; j < 8; j++) { float d = v8[j] - mean; vs += d * d; }
    }
    #pragma unroll
    for (int o = 32; o > 0; o >>= 1) vs += __shfl_xor(vs, o);
    if ((tid & 63) == 0) wvar[tid >> 6] = vs;
    __syncthreads();
    float inv = 1.0f / sqrtf((wvar[0] + wvar[1]) * (1.0f / H_) + 1e-12f);
    if (act) {
        float o8[8];
        #pragma unroll
        for (int j = 0; j < 8; j++) o8[j] = (v8[j] - mean) * inv * g[idx + j] + bb[idx + j];
        us8 h, l; pack8(o8, h, l);
        unsigned short* p = out_pk + ((size_t)tok * 96 + tid) * 16;
        *reinterpret_cast<us8*>(p) = h;
        *reinterpret_cast<us8*>(p + 8) = l;
    }
}

// ================= residual + LN (in-place packed) =================
__global__ __launch_bounds__(128) void k_res_ln(
    const float* __restrict__ x, const float* __restrict__ g, const float* __restrict__ bb,
    unsigned short* __restrict__ h_pk)
{
    int tok = blockIdx.x;
    int tid = threadIdx.x;
    bool act = tid < 96;
    int idx = tid * 8;
    float v8[8];
    float sum = 0.f;
    unsigned short* p = h_pk + ((size_t)tok * 96 + tid) * 16;
    if (act) {
        const float4* x4 = reinterpret_cast<const float4*>(x + (size_t)tok * H_ + idx);
        us8 hi = *reinterpret_cast<const us8*>(p);
        us8 lo = *reinterpret_cast<const us8*>(p + 8);
        float4 a0 = x4[0], a1 = x4[1];
        float xs[8] = {a0.x, a0.y, a0.z, a0.w, a1.x, a1.y, a1.z, a1.w};
        #pragma unroll
        for (int j = 0; j < 8; j++) {
            v8[j] = xs[j] + bf2f(hi[j]) + bf2f(lo[j]);
            sum += v8[j];
        }
    }
    __shared__ float wsum[2], wvar[2];
    #pragma unroll
    for (int o = 32; o > 0; o >>= 1) sum += __shfl_xor(sum, o);
    if ((tid & 63) == 0) wsum[tid >> 6] = sum;
    __syncthreads();
    float mean = (wsum[0] + wsum[1]) * (1.0f / H_);
    float vs = 0.f;
    if (act) {
        for (int j = 0; j < 8; j++) { float d = v8[j] - mean; vs += d * d; }
    }
    #pragma unroll
    for (int o = 32; o > 0; o >>= 1) vs += __shfl_xor(vs, o);
    if ((tid & 63) == 0) wvar[tid >> 6] = vs;
    __syncthreads();
    float inv = 1.0f / sqrtf((wvar[0] + wvar[1]) * (1.0f / H_) + 1e-12f);
    if (act) {
        float o8[8];
        #pragma unroll
        for (int j = 0; j < 8; j++) o8[j] = (v8[j] - mean) * inv * g[idx + j] + bb[idx + j];
        us8 h, l; pack8(o8, h, l);
        *reinterpret_cast<us8*>(p) = h;
        *reinterpret_cast<us8*>(p + 8) = l;
    }
}

// ================= packed MFMA GEMM: 3-buffer, ONE barrier/K-step, counted vmcnt =================
__global__ __launch_bounds__(256) void k_gemm_pk(
    const unsigned short* __restrict__ A, const unsigned short* __restrict__ Wp,
    const float* __restrict__ bias,
    float* __restrict__ C0, float* __restrict__ C1, float* __restrict__ C2, int cpb,
    unsigned short* __restrict__ Cpk,
    int M, int N, int K, int act, int cbx)
{
    constexpr int BUFSZ = 24576;               // A 16KB + B 8KB
    __shared__ char smem[3 * BUFSZ];
    unsigned smb = (unsigned)(size_t)(void*)smem;

    int id = blockIdx.x;
    int xcd = id & 7;
    int rr = id >> 3;
    int by = (xcd >> 1) * 8 + rr / cbx;
    int bx = (xcd & 1) * cbx + rr % cbx;
    int m0 = by << 7, n0 = bx << 6;
    int Kb = K >> 3;
    int nst = Kb >> 2;
    int rowbytes = Kb * 32;

    int tid = threadIdx.x;
    int lane = tid & 63, wid = tid >> 6;
    int wm = wid >> 1, wn = wid & 1;
    int fr = lane & 15, fq = lane >> 4;

    f4 acc[4][2];
    #pragma unroll
    for (int i = 0; i < 4; i++)
        #pragma unroll
        for (int j = 0; j < 2; j++) acc[i][j] = (f4){0.f, 0.f, 0.f, 0.f};

    const char* agp[4];
    const char* bgp[2];
    #pragma unroll
    for (int i = 0; i < 4; i++) {
        int d = i * 4096 + tid * 16;
        int row = d >> 7;
        int colp = (d & 127) ^ ((row & 7) << 4);
        agp[i] = (const char*)A + (size_t)(m0 + row) * rowbytes + colp;
    }
    #pragma unroll
    for (int i = 0; i < 2; i++) {
        int d = i * 4096 + tid * 16;
        int row = d >> 7;
        int colp = (d & 127) ^ ((row & 7) << 4);
        bgp[i] = (const char*)Wp + (size_t)(n0 + row) * rowbytes + colp;
    }

    int afo[4], bfo[2];
    #pragma unroll
    for (int mi = 0; mi < 4; mi++) {
        int r = wm * 64 + mi * 16 + fr;
        afo[mi] = r * 128 + ((fq * 32) ^ ((r & 7) << 4));
    }
    #pragma unroll
    for (int ni = 0; ni < 2; ni++) {
        int rb = wn * 32 + ni * 16 + fr;
        bfo[ni] = 16384 + rb * 128 + ((fq * 32) ^ ((rb & 7) << 4));
    }

    auto issue = [&](int ks, unsigned boff) {
        size_t ko = (size_t)ks * 128;
        #pragma unroll
        for (int i = 0; i < 4; i++)
            __builtin_amdgcn_global_load_lds((const AS1 void*)(size_t)(agp[i] + ko),
                (AS3 void*)(unsigned)(smb + boff + i * 4096 + wid * 1024), 16, 0, 0);
        #pragma unroll
        for (int i = 0; i < 2; i++)
            __builtin_amdgcn_global_load_lds((const AS1 void*)(size_t)(bgp[i] + ko),
                (AS3 void*)(unsigned)(smb + boff + 16384 + i * 4096 + wid * 1024), 16, 0, 0);
    };

    issue(0, 0);
    if (nst > 1) issue(1, BUFSZ);
    unsigned c0 = 0, c1 = BUFSZ, c2 = 2 * BUFSZ;

    for (int ks = 0; ks < nst; ks++) {
        if (ks + 1 < nst) asm volatile("s_waitcnt vmcnt(6)" ::: "memory");
        else              asm volatile("s_waitcnt vmcnt(0)" ::: "memory");
        __builtin_amdgcn_s_barrier();
        __builtin_amdgcn_sched_barrier(0);
        if (ks + 2 < nst) issue(ks + 2, c2);

        const char* cbp = smem + c0;
        bfrag ah[4], al[4], bh[2], bl[2];
        #pragma unroll
        for (int mi = 0; mi < 4; mi++) {
            ah[mi] = *reinterpret_cast<const bfrag*>(cbp + afo[mi]);
            al[mi] = *reinterpret_cast<const bfrag*>(cbp + (afo[mi] ^ 16));
        }
        #pragma unroll
        for (int ni = 0; ni < 2; ni++) {
            bh[ni] = *reinterpret_cast<const bfrag*>(cbp + bfo[ni]);
            bl[ni] = *reinterpret_cast<const bfrag*>(cbp + (bfo[ni] ^ 16));
        }
        #pragma unroll
        for (int mi = 0; mi < 4; mi++) {
            #pragma unroll
            for (int ni = 0; ni < 2; ni++) {
                acc[mi][ni] = __builtin_amdgcn_mfma_f32_16x16x32_bf16(ah[mi], bh[ni], acc[mi][ni], 0, 0, 0);
                acc[mi][ni] = __builtin_amdgcn_mfma_f32_16x16x32_bf16(ah[mi], bl[ni], acc[mi][ni], 0, 0, 0);
                acc[mi][ni] = __builtin_amdgcn_mfma_f32_16x16x32_bf16(al[mi], bh[ni], acc[mi][ni], 0, 0, 0);
            }
        }
        unsigned t = c0; c0 = c1; c1 = c2; c2 = t;
    }

    if (act == 0) {
        #pragma unroll
        for (int mi = 0; mi < 4; mi++) {
            #pragma unroll
            for (int ni = 0; ni < 2; ni++) {
                int col = n0 + wn * 32 + ni * 16 + fr;
                float bv = bias[col];
                int buf = col / cpb;
                float* Cp = (buf == 0) ? C0 : (buf == 1) ? C1 : C2;
                int cc = col - buf * cpb;
                #pragma unroll
                for (int r = 0; r < 4; r++) {
                    int row = m0 + wm * 64 + mi * 16 + fq * 4 + r;
                    Cp[(size_t)row * cpb + cc] = acc[mi][ni][r] + bv;
                }
            }
        }
    } else {
        __syncthreads();
        float* ebuf = (float*)(smem + wid * 2432);
        int Nb = N >> 3;
        #pragma unroll
        for (int mi = 0; mi < 4; mi++) {
            #pragma unroll
            for (int ni = 0; ni < 2; ni++) {
                int col = n0 + wn * 32 + ni * 16 + fr;
                float bv = bias[col];
                #pragma unroll
                for (int r = 0; r < 4; r++) {
                    float v = acc[mi][ni][r] + bv;
                    v = 0.5f * v * (1.0f + erff(v * 0.70710678118654752f));
                    ebuf[(fq * 4 + r) * 38 + ni * 16 + fr] = v;
                }
            }
            int row16 = lane >> 2, kb = lane & 3;
            float v8[8];
            #pragma unroll
            for (int j = 0; j < 8; j++) v8[j] = ebuf[row16 * 38 + kb * 8 + j];
            us8 h, l; pack8(v8, h, l);
            int grow = m0 + wm * 64 + mi * 16 + row16;
            int gcb = ((n0 + wn * 32) >> 3) + kb;
            unsigned short* p = Cpk + ((size_t)grow * Nb + gcb) * 16;
            *reinterpret_cast<us8*>(p) = h;
            *reinterpret_cast<us8*>(p + 8) = l;
        }
    }
}

// ================= fused flash attention (exp2-domain online softmax) =================
#define SM_KH 0
#define SM_KL 5632
#define SM_VH 11264
#define SM_VL 16384
#define SM_PH 21504
#define SM_PL 26624
__global__ __launch_bounds__(256) void k_attn_fused(
    const float* __restrict__ Q, const float* __restrict__ Kb,
    const float* __restrict__ V, const int* __restrict__ amask,
    unsigned short* __restrict__ ctx_pk)
{
    __shared__ char smem[31744];
    unsigned short* KhS = (unsigned short*)(smem + SM_KH);
    unsigned short* KlS = (unsigned short*)(smem + SM_KL);
    unsigned short* VhS = (unsigned short*)(smem + SM_VH);
    unsigned short* VlS = (unsigned short*)(smem + SM_VL);
    unsigned short* PhS = (unsigned short*)(smem + SM_PH);
    unsigned short* PlS = (unsigned short*)(smem + SM_PL);

    int idx = blockIdx.x;
    int qt = idx & 3;
    int hd = (idx >> 2) % NH_;
    int b = idx / (4 * NH_);
    int tid = threadIdx.x;
    int lane = tid & 63, wid = tid >> 6;
    int fr = lane & 15, fq = lane >> 4;

    int q0 = qt * 64 + wid * 16;

    bfrag qh[2], ql[2];
    {
        const float* qbase = Q + ((size_t)(b * S_ + q0 + fr)) * H_ + hd * DH_;
        #pragma unroll
        for (int ks = 0; ks < 2; ks++) {
            const float4* p = reinterpret_cast<const float4*>(qbase + ks * 32 + fq * 8);
            float4 v0 = p[0], v1 = p[1];
            float vv[8] = {v0.x, v0.y, v0.z, v0.w, v1.x, v1.y, v1.z, v1.w};
            #pragma unroll
            for (int j = 0; j < 8; j++) {
                unsigned short h = f2bf(vv[j]);
                qh[ks][j] = (short)h;
                ql[ks][j] = (short)f2bf(vv[j] - bf2f(h));
            }
        }
    }

    f4 o[4];
    #pragma unroll
    for (int i = 0; i < 4; i++) o[i] = (f4){0.f, 0.f, 0.f, 0.f};
    float m[4], l[4];
    #pragma unroll
    for (int r = 0; r < 4; r++) { m[r] = -3e38f; l[r] = 0.f; }

    int kvrow = tid >> 3;
    int dbase = (tid & 7) * 8;

    const float SCL2 = 0.125f * LOG2E_;
    const float MB2  = -1e9f * LOG2E_;

    for (int t = 0; t < 8; t++) {
        {
            const float* src = Kb + ((size_t)(b * S_ + t * 32 + kvrow)) * H_ + hd * DH_ + dbase;
            float4 a4 = reinterpret_cast<const float4*>(src)[0];
            float4 b4 = reinterpret_cast<const float4*>(src)[1];
            float vv[8] = {a4.x, a4.y, a4.z, a4.w, b4.x, b4.y, b4.z, b4.w};
            us8 h, l2;
            #pragma unroll
            for (int j = 0; j < 8; j++) {
                unsigned short hh = f2bf(vv[j]);
                h[j] = hh; l2[j] = f2bf(vv[j] - bf2f(hh));
            }
            *reinterpret_cast<us8*>(&KhS[kvrow * 88 + dbase]) = h;
            *reinterpret_cast<us8*>(&KlS[kvrow * 88 + dbase]) = l2;
        }
        {
            const float* src = V + ((size_t)(b * S_ + t * 32 + kvrow)) * H_ + hd * DH_ + dbase;
            float4 a4 = reinterpret_cast<const float4*>(src)[0];
            float4 b4 = reinterpret_cast<const float4*>(src)[1];
            float vv[8] = {a4.x, a4.y, a4.z, a4.w, b4.x, b4.y, b4.z, b4.w};
            #pragma unroll
            for (int j = 0; j < 8; j++) {
                unsigned short h = f2bf(vv[j]);
                VhS[(dbase + j) * 40 + kvrow] = h;
                VlS[(dbase + j) * 40 + kvrow] = f2bf(vv[j] - bf2f(h));
            }
        }
        __syncthreads();

        f4 s0 = (f4){0.f,0.f,0.f,0.f}, s1 = (f4){0.f,0.f,0.f,0.f};
        #pragma unroll
        for (int ks = 0; ks < 2; ks++) {
            bfrag kbh0 = *reinterpret_cast<const bfrag*>(&KhS[fr * 88 + ks * 32 + fq * 8]);
            bfrag kbl0 = *reinterpret_cast<const bfrag*>(&KlS[fr * 88 + ks * 32 + fq * 8]);
            bfrag kbh1 = *reinterpret_cast<const bfrag*>(&KhS[(16 + fr) * 88 + ks * 32 + fq * 8]);
            bfrag kbl1 = *reinterpret_cast<const bfrag*>(&KlS[(16 + fr) * 88 + ks * 32 + fq * 8]);
            s0 = __builtin_amdgcn_mfma_f32_16x16x32_bf16(qh[ks], kbh0, s0, 0, 0, 0);
            s0 = __builtin_amdgcn_mfma_f32_16x16x32_bf16(qh[ks], kbl0, s0, 0, 0, 0);
            s0 = __builtin_amdgcn_mfma_f32_16x16x32_bf16(ql[ks], kbh0, s0, 0, 0, 0);
            s1 = __builtin_amdgcn_mfma_f32_16x16x32_bf16(qh[ks], kbh1, s1, 0, 0, 0);
            s1 = __builtin_amdgcn_mfma_f32_16x16x32_bf16(qh[ks], kbl1, s1, 0, 0, 0);
            s1 = __builtin_amdgcn_mfma_f32_16x16x32_bf16(ql[ks], kbh1, s1, 0, 0, 0);
        }

        float cb0 = (amask[b * S_ + t * 32 + fr] == 0) ? MB2 : 0.f;
        float cb1 = (amask[b * S_ + t * 32 + 16 + fr] == 0) ? MB2 : 0.f;
        float sc0[4], sc1[4], fct[4], pr0[4], pr1[4];
        #pragma unroll
        for (int r = 0; r < 4; r++) {
            sc0[r] = s0[r] * SCL2 + cb0;
            sc1[r] = s1[r] * SCL2 + cb1;
            float tm = fmaxf(sc0[r], sc1[r]);
            #pragma unroll
            for (int od = 1; od < 16; od <<= 1) tm = fmaxf(tm, __shfl_xor(tm, od));
            float mn = fmaxf(m[r], tm);
            fct[r] = exp2f(m[r] - mn);
            pr0[r] = exp2f(sc0[r] - mn);
            pr1[r] = exp2f(sc1[r] - mn);
            float rs = pr0[r] + pr1[r];
            #pragma unroll
            for (int od = 1; od < 16; od <<= 1) rs += __shfl_xor(rs, od);
            l[r] = l[r] * fct[r] + rs;
            m[r] = mn;
        }
        #pragma unroll
        for (int ci = 0; ci < 4; ci++)
            #pragma unroll
            for (int r = 0; r < 4; r++) o[ci][r] *= fct[r];

        #pragma unroll
        for (int r = 0; r < 4; r++) {
            int row = fq * 4 + r;
            unsigned short h0 = f2bf(pr0[r]);
            PhS[wid * 640 + row * 40 + fr] = h0;
            PlS[wid * 640 + row * 40 + fr] = f2bf(pr0[r] - bf2f(h0));
            unsigned short h1 = f2bf(pr1[r]);
            PhS[wid * 640 + row * 40 + 16 + fr] = h1;
            PlS[wid * 640 + row * 40 + 16 + fr] = f2bf(pr1[r] - bf2f(h1));
        }

        bfrag pah = *reinterpret_cast<const bfrag*>(&PhS[wid * 640 + fr * 40 + fq * 8]);
        bfrag pal = *reinterpret_cast<const bfrag*>(&PlS[wid * 640 + fr * 40 + fq * 8]);
        #pragma unroll
        for (int ci = 0; ci < 4; ci++) {
            bfrag vbh = *reinterpret_cast<const bfrag*>(&VhS[(ci * 16 + fr) * 40 + fq * 8]);
            bfrag vbl = *reinterpret_cast<const bfrag*>(&VlS[(ci * 16 + fr) * 40 + fq * 8]);
            o[ci] = __builtin_amdgcn_mfma_f32_16x16x32_bf16(pah, vbh, o[ci], 0, 0, 0);
            o[ci] = __builtin_amdgcn_mfma_f32_16x16x32_bf16(pah, vbl, o[ci], 0, 0, 0);
            o[ci] = __builtin_amdgcn_mfma_f32_16x16x32_bf16(pal, vbh, o[ci], 0, 0, 0);
        }
        __syncthreads();
    }

    __syncthreads();
    float* eb = (float*)smem + wid * 1088;
    #pragma unroll
    for (int r = 0; r < 4; r++) {
        float inv = 1.0f / l[r];
        #pragma unroll
        for (int ci = 0; ci < 4; ci++)
            eb[(fq * 4 + r) * 68 + ci * 16 + fr] = o[ci][r] * inv;
    }
    __syncthreads();
    #pragma unroll
    for (int e = 0; e < 2; e++) {
        int item = lane * 2 + e;
        int row16 = item >> 3, kb = item & 7;
        float v8[8];
        #pragma unroll
        for (int j = 0; j < 8; j++) v8[j] = eb[row16 * 68 + kb * 8 + j];
        us8 h, l2; pack8(v8, h, l2);
        int grow = b * S_ + q0 + row16;
        int gcb = hd * 8 + kb;
        unsigned short* p = ctx_pk + ((size_t)grow * 96 + gcb) * 16;
        *reinterpret_cast<us8*>(p) = h;
        *reinterpret_cast<us8*>(p + 8) = l2;
    }
}

// ================= classifier (packed h) =================
__global__ __launch_bounds__(64) void k_classifier(
    const unsigned short* __restrict__ Hpk, const float* __restrict__ Wc,
    const float* __restrict__ bc, float* __restrict__ logits)
{
    int tok = blockIdx.x;
    int lane = threadIdx.x;
    float acc[T_];
    #pragma unroll
    for (int j = 0; j < T_; j++) acc[j] = 0.f;
    for (int kb = lane; kb < 96; kb += 64) {
        const unsigned short* p = Hpk + ((size_t)tok * 96 + kb) * 16;
        us8 hi = *reinterpret_cast<const us8*>(p);
        us8 lo = *reinterpret_cast<const us8*>(p + 8);
        #pragma unroll
        for (int e = 0; e < 8; e++) {
            float hv = bf2f(hi[e]) + bf2f(lo[e]);
            const float* wr = Wc + (size_t)(kb * 8 + e) * T_;
            #pragma unroll
            for (int j = 0; j < T_; j++) acc[j] = fmaf(hv, wr[j], acc[j]);
        }
    }
    #pragma unroll
    for (int j = 0; j < T_; j++) {
        float v = acc[j];
        for (int o = 32; o > 0; o >>= 1) v += __shfl_down(v, o);
        if (lane == 0) logits[(size_t)tok * T_ + j] = v + bc[j];
    }
}

// ================= fused CRF + Viterbi (drop-max LSE, renorm/8, 8-deep em ring) =================
__global__ __launch_bounds__(256) void k_crf_vit(
    const float* __restrict__ logits, const int* __restrict__ amask,
    const int* __restrict__ labels, const float* __restrict__ start,
    const float* __restrict__ endv, const float* __restrict__ trans,
    float* __restrict__ out)
{
    int blk = blockIdx.x;
    int tid = threadIdx.x;
    if (blk == 0) {
        __shared__ float res[B_];
        int lane = tid & 63;
        int bb = (tid >> 6) * 4 + (lane >> 4);
        int sj = lane & 15;
        int lb = lane & 48;

        int cnt = 0;
        for (int s = sj; s < S_; s += 16) cnt += amask[bb * S_ + s];
        #pragma unroll
        for (int o = 8; o > 0; o >>= 1) cnt += __shfl_xor(cnt, o);
        int len = cnt;
        int lim = len - 1;

        float num = 0.f;
        for (int s = 2 + sj; s < S_; s += 16) {
            if (s < lim) {
                int tp = labels[bb * S_ + s - 1];
                int tc = labels[bb * S_ + s];
                num += trans[tp * T_ + tc] + logits[((size_t)(bb * S_ + s)) * T_ + tc];
            }
        }
        #pragma unroll
        for (int o = 8; o > 0; o >>= 1) num += __shfl_xor(num, o);
        int tg1 = labels[bb * S_ + 1];
        num += start[tg1] + logits[((size_t)(bb * S_ + 1)) * T_ + tg1];
        num += endv[labels[bb * S_ + (len - 2)]];

        float tc9[T_];
        #pragma unroll
        for (int i = 0; i < T_; i++) tc9[i] = (sj < T_) ? trans[i * T_ + sj] * LOG2E_ : 0.f;
        float score = (sj < T_) ? (start[sj] + logits[((size_t)(bb * S_ + 1)) * T_ + sj]) * LOG2E_ : 0.f;
        float base = 0.f;
        const float* embase = logits + (size_t)bb * S_ * T_ + sj;
        float emb[8];
        #pragma unroll
        for (int c = 0; c < 8; c++) emb[c] = (sj < T_) ? embase[(2 + c) * T_] : 0.f;
        for (int s0 = 2; s0 < S_; s0 += 8) {
            #pragma unroll
            for (int c = 0; c < 8; c++) {
                int s = s0 + c;
                if (s < S_) {
                    float em = emb[c];
                    emb[c] = (sj < T_ && s + 8 < S_) ? embase[(size_t)(s + 8) * T_] : 0.f;
                    float si[T_];
                    #pragma unroll
                    for (int i = 0; i < T_; i++) si[i] = __shfl(score, lb + i);
                    float e2[T_];
                    #pragma unroll
                    for (int i = 0; i < T_; i++) e2[i] = exp2f(si[i] + tc9[i]);
                    float s01 = e2[0] + e2[1], s23 = e2[2] + e2[3];
                    float s45 = e2[4] + e2[5], s67 = e2[6] + e2[7];
                    float sum = ((s01 + s23) + (s45 + s67)) + e2[8];
                    float nsc = fmaf(em, LOG2E_, log2f(sum));
                    if (s < lim) score = nsc;
                }
            }
            float sh = __shfl(score, lb);
            score -= sh;
            base += sh;
        }
        float se = (sj < T_) ? score + endv[sj] * LOG2E_ : -1e30f;
        float fi[T_];
        #pragma unroll
        for (int i = 0; i < T_; i++) fi[i] = __shfl(se, lb + i);
        if (sj == 0) {
            float mx = -1e30f;
            #pragma unroll
            for (int i = 0; i < T_; i++) mx = fmaxf(mx, fi[i]);
            float sum = 0.f;
            #pragma unroll
            for (int i = 0; i < T_; i++) sum += exp2f(fi[i] - mx);
            res[bb] = (base + mx + log2f(sum)) * LN2_ - num;
        }
        __syncthreads();
        if (tid == 0) {
            float tot = 0.f;
            #pragma unroll
            for (int i = 0; i < B_; i++) tot += res[i];
            out[0] = tot;
        }
    } else {
        if (tid >= 64) return;
        int b = blk - 1;
        int j = tid;
        float* tags_out = out + 1;
        __shared__ unsigned char hist[S_ - 1][T_];
        float tc9[T_];
        #pragma unroll
        for (int i = 0; i < T_; i++) tc9[i] = (j < T_) ? trans[i * T_ + j] : 0.f;
        float score = (j < T_) ? start[j] + logits[((size_t)(b * S_)) * T_ + j] : -1e30f;
        const float* embase = logits + (size_t)b * S_ * T_ + j;
        float emb[8];
        #pragma unroll
        for (int c = 0; c < 8; c++) emb[c] = (j < T_) ? embase[(1 + c) * T_] : 0.f;
        for (int t0 = 1; t0 < S_; t0 += 8) {
            #pragma unroll
            for (int c = 0; c < 8; c++) {
                int t = t0 + c;
                if (t < S_) {
                    float em = emb[c];
                    emb[c] = (j < T_ && t + 8 < S_) ? embase[(size_t)(t + 8) * T_] : 0.f;
                    float si[T_];
                    #pragma unroll
                    for (int i = 0; i < T_; i++) si[i] = __shfl(score, i);
                    float cv[T_];
                    #pragma unroll
                    for (int i = 0; i < T_; i++) cv[i] = si[i] + tc9[i];
                    float v01 = cv[0]; int i01 = 0; if (cv[1] > v01) { v01 = cv[1]; i01 = 1; }
                    float v23 = cv[2]; int i23 = 2; if (cv[3] > v23) { v23 = cv[3]; i23 = 3; }
                    float v45 = cv[4]; int i45 = 4; if (cv[5] > v45) { v45 = cv[5]; i45 = 5; }
                    float v67 = cv[6]; int i67 = 6; if (cv[7] > v67) { v67 = cv[7]; i67 = 7; }
                    float v03 = v01; int i03 = i01; if (v23 > v03) { v03 = v23; i03 = i23; }
                    float v47 = v45; int i47 = i45; if (v67 > v47) { v47 = v67; i47 = i67; }
                    float v07 = v03; int i07 = i03; if (v47 > v07) { v07 = v47; i07 = i47; }
                    float best = v07; int bi = i07; if (cv[8] > best) { best = cv[8]; bi = 8; }
                    if (j < T_) {
                        hist[t - 1][j] = (unsigned char)bi;
                        score = best + em;
                    }
                }
            }
        }
        float se = (j < T_) ? score + endv[j] : -1e30f;
        float fi[T_];
        #pragma unroll
        for (int i = 0; i < T_; i++) fi[i] = __shfl(se, i);
        if (j == 0) {
            float best = -1e30f; int last = 0;
            #pragma unroll
            for (int i = 0; i < T_; i++) if (fi[i] > best) { best = fi[i]; last = i; }
            tags_out[b * S_ + (S_ - 1)] = (float)last;
            int cur = last;
            for (int t = S_ - 2; t >= 0; t--) {
                cur = hist[t][cur];
                tags_out[b * S_ + t] = (float)cur;
            }
        }
    }
}

// ================= driver =================
extern "C" void kernel_launch(void* const* d_in, const int* in_sizes, int n_in,
                              void* d_out, int out_size, void* d_ws, size_t ws_size,
                              hipStream_t stream)
{
    const int*   input_ids = (const int*)d_in[0];
    const int*   amask     = (const int*)d_in[1];
    const int*   labels    = (const int*)d_in[2];
    const float* word_emb  = (const float*)d_in[3];
    const float* pos_emb   = (const float*)d_in[4];
    const float* type_emb  = (const float*)d_in[5];
    const float* emb_g     = (const float*)d_in[6];
    const float* emb_b     = (const float*)d_in[7];
    const float* lWq = (const float*)d_in[8];
    const float* lbq = (const float*)d_in[9];
    const float* lWk = (const float*)d_in[10];
    const float* lbk = (const float*)d_in[11];
    const float* lWv = (const float*)d_in[12];
    const float* lbv = (const float*)d_in[13];
    const float* lWo = (const float*)d_in[14];
    const float* lbo = (const float*)d_in[15];
    const float* lg1 = (const float*)d_in[16];
    const float* lb1 = (const float*)d_in[17];
    const float* lWi = (const float*)d_in[18];
    const float* lbi = (const float*)d_in[19];
    const float* lWf = (const float*)d_in[20];
    const float* lbf = (const float*)d_in[21];
    const float* lg2 = (const float*)d_in[22];
    const float* lb2 = (const float*)d_in[23];
    const float* cls_W = (const float*)d_in[24];
    const float* cls_b = (const float*)d_in[25];
    const float* crf_start = (const float*)d_in[26];
    const float* crf_end   = (const float*)d_in[27];
    const float* crf_trans = (const float*)d_in[28];

    float* out = (float*)d_out;
    float* ws = (float*)d_ws;

    const size_t NH32 = (size_t)NTOK * H_;
    float* h_pk_f  = ws + NH32;
    float* q       = ws + 2 * NH32;
    float* kbuf    = ws + 3 * NH32;
    float* v       = ws + 4 * NH32;
    float* ctxpk_f = ws + 5 * NH32;
    float* tmp     = ws + 6 * NH32;
    float* Wpk_f   = ws + 7 * NH32;
    float* qkvbias = Wpk_f + 7077888;
    float* logits  = qkvbias + 3 * H_;

    unsigned short* h_pk   = (unsigned short*)h_pk_f;
    unsigned short* ctx_pk = (unsigned short*)ctxpk_f;
    unsigned short* Wpk    = (unsigned short*)Wpk_f;
    unsigned short* big_pk = (unsigned short*)q;

    k_embed_ln<<<NTOK, 128, 0, stream>>>(input_ids, word_emb, pos_emb, type_emb, emb_g, emb_b, h_pk);

    const size_t WOFF_O = 221184, WOFF_I = 294912, WOFF_F = 589824;

    for (int l = 0; l < L_; l++) {
        k_conv_w<<<1728, 256, 0, stream>>>(
            lWq + (size_t)l * H_ * H_, lWk + (size_t)l * H_ * H_,
            lWv + (size_t)l * H_ * H_, lWo + (size_t)l * H_ * H_,
            lWi + (size_t)l * H_ * FF_, lWf + (size_t)l * FF_ * H_,
            lbq + (size_t)l * H_, lbk + (size_t)l * H_, lbv + (size_t)l * H_,
            qkvbias, Wpk);

        // fused QKV: N = 2304 -> 32x36 blocks, chunk 8x18
        k_gemm_pk<<<1152, 256, 0, stream>>>(h_pk, Wpk, qkvbias,
            q, kbuf, v, H_, nullptr, NTOK, 3 * H_, H_, 0, 18);

        k_attn_fused<<<B_ * NH_ * 4, 256, 0, stream>>>(q, kbuf, v, amask, ctx_pk);

        // attn-out: N = 768 -> 32x12 blocks, chunk 8x6
        k_gemm_pk<<<384, 256, 0, stream>>>(ctx_pk, Wpk + WOFF_O * 16, lbo + (size_t)l * H_,
            tmp, tmp, tmp, H_, nullptr, NTOK, H_, H_, 0, 6);

        k_res_ln<<<NTOK, 128, 0, stream>>>(tmp, lg1 + (size_t)l * H_, lb1 + (size_t)l * H_, h_pk);

        // FF1: N = 3072 -> 32x48 blocks, chunk 8x24
        k_gemm_pk<<<1536, 256, 0, stream>>>(h_pk, Wpk + WOFF_I * 16, lbi + (size_t)l * FF_,
            tmp, tmp, tmp, FF_, big_pk, NTOK, FF_, H_, 1, 24);

        // FF2: N = 768, K = 3072 -> 32x12 blocks, chunk 8x6
        k_gemm_pk<<<384, 256, 0, stream>>>(big_pk, Wpk + WOFF_F * 16, lbf + (size_t)l * H_,
            tmp, tmp, tmp, H_, nullptr, NTOK, H_, FF_, 0, 6);

        k_res_ln<<<NTOK, 128, 0, stream>>>(tmp, lg2 + (size_t)l * H_, lb2 + (size_t)l * H_, h_pk);
    }

    k_classifier<<<NTOK, 64, 0, stream>>>(h_pk, cls_W, cls_b, logits);
    k_crf_vit<<<1 + B_, 256, 0, stream>>>(logits, amask, labels, crf_start, crf_end, crf_trans, out);
}